// Round 5
// baseline (303.016 us; speedup 1.0000x reference)
//
#include <hip/hip_runtime.h>
#include <stdint.h>

#define T 2048
#define D 512
#define NH 8
#define DH 64
#define L 2

typedef float floatx4 __attribute__((ext_vector_type(4)));
typedef short shortx8 __attribute__((ext_vector_type(8)));
typedef unsigned short u16;
typedef unsigned short u16x4 __attribute__((ext_vector_type(4)));

__device__ __forceinline__ u16 f2bf(float f) {
    union { float f; uint32_t u; } c; c.f = f;
    uint32_t u = c.u;
    u += 0x7fffu + ((u >> 16) & 1u);
    return (u16)(u >> 16);
}

__device__ __forceinline__ float bf2f(u16 v) {
    union { uint32_t u; float f; } c; c.u = ((uint32_t)v) << 16;
    return c.f;
}

__device__ __forceinline__ void load_lds16(const void* g, void* l) {
    __builtin_amdgcn_global_load_lds((const __attribute__((address_space(1))) void*)g,
                                     (__attribute__((address_space(3))) void*)l,
                                     16, 0, 0);
}

// ---------------- pre: weight transposes (z<24) + add_pos (z==24) ----------
struct TransJobs {
    const float* src[6];
    u16* dst[6];
    const float* x;
    const float* pos;
    u16* h;
};

__global__ __launch_bounds__(256) void pre_kernel(TransJobs j) {
    __shared__ float tile[32][33];
    int tid = threadIdx.x;
    if (blockIdx.z == 24) {
        int idx = (blockIdx.y * 32 + blockIdx.x) * 256 + tid;  // float4 index
        float4 xv = ((const float4*)j.x)[idx];
        float4 pv = ((const float4*)j.pos)[idx];
        u16x4 hh;
        hh[0] = f2bf(xv.x + pv.x); hh[1] = f2bf(xv.y + pv.y);
        hh[2] = f2bf(xv.z + pv.z); hh[3] = f2bf(xv.w + pv.w);
        ((u16x4*)j.h)[idx] = hh;
        ((u16x4*)j.h)[idx + (T * D / 4)] = hh;
        return;
    }
    int m = blockIdx.z >> 2, slice = blockIdx.z & 3;
    int R = (m == 5) ? 1024 : 512;
    int C = (m == 4) ? 1024 : 512;
    if (blockIdx.x * 32 >= C || blockIdx.y * 32 >= R) return;
    const float* in = j.src[m] + (size_t)slice * R * C;
    u16* out = j.dst[m] + (size_t)slice * R * C;
    int tx = tid & 31, ty = tid >> 5;
    int x = blockIdx.x * 32 + tx;
    int y0 = blockIdx.y * 32;
#pragma unroll
    for (int i = 0; i < 4; i++)
        tile[ty + i * 8][tx] = in[(size_t)(y0 + ty + i * 8) * C + x];
    __syncthreads();
    int ox = y0 + tx;
#pragma unroll
    for (int i = 0; i < 4; i++)
        out[(size_t)(blockIdx.x * 32 + ty + i * 8) * R + ox] = f2bf(tile[tx][ty + i * 8]);
}

// ---------------- LayerNorm over bf16 h + optional bf16-partial fold -------
__global__ __launch_bounds__(256) void ln_res_kernel(u16* __restrict__ h,
                                                     const u16* __restrict__ part,
                                                     const float* __restrict__ wp,
                                                     const float* __restrict__ bp,
                                                     u16* __restrict__ out, int l) {
    int row = blockIdx.x * 4 + (threadIdx.x >> 6);
    int lane = threadIdx.x & 63;
    int s = row >> 11;
    int c0 = lane * 4;
    u16* xr = h + (size_t)row * D;
    u16x4 h0 = *(const u16x4*)(xr + c0);
    u16x4 h1 = *(const u16x4*)(xr + c0 + 256);
    float4 v0, v1;
    v0.x = bf2f(h0[0]); v0.y = bf2f(h0[1]); v0.z = bf2f(h0[2]); v0.w = bf2f(h0[3]);
    v1.x = bf2f(h1[0]); v1.y = bf2f(h1[1]); v1.z = bf2f(h1[2]); v1.w = bf2f(h1[3]);
    if (part) {
        const u16* p0r = part + (size_t)s * 2 * T * D + (size_t)(row & (T - 1)) * D;
        const u16* p1r = p0r + (size_t)T * D;
        u16x4 a0 = *(const u16x4*)(p0r + c0), a1 = *(const u16x4*)(p0r + c0 + 256);
        u16x4 e0 = *(const u16x4*)(p1r + c0), e1 = *(const u16x4*)(p1r + c0 + 256);
        v0.x += bf2f(a0[0]) + bf2f(e0[0]); v0.y += bf2f(a0[1]) + bf2f(e0[1]);
        v0.z += bf2f(a0[2]) + bf2f(e0[2]); v0.w += bf2f(a0[3]) + bf2f(e0[3]);
        v1.x += bf2f(a1[0]) + bf2f(e1[0]); v1.y += bf2f(a1[1]) + bf2f(e1[1]);
        v1.z += bf2f(a1[2]) + bf2f(e1[2]); v1.w += bf2f(a1[3]) + bf2f(e1[3]);
        u16x4 s0, s1;
        s0[0] = f2bf(v0.x); s0[1] = f2bf(v0.y); s0[2] = f2bf(v0.z); s0[3] = f2bf(v0.w);
        s1[0] = f2bf(v1.x); s1[1] = f2bf(v1.y); s1[2] = f2bf(v1.z); s1[3] = f2bf(v1.w);
        *(u16x4*)(xr + c0) = s0;
        *(u16x4*)(xr + c0 + 256) = s1;
    }
    float sum = v0.x + v0.y + v0.z + v0.w + v1.x + v1.y + v1.z + v1.w;
    float sq = v0.x*v0.x + v0.y*v0.y + v0.z*v0.z + v0.w*v0.w
             + v1.x*v1.x + v1.y*v1.y + v1.z*v1.z + v1.w*v1.w;
#pragma unroll
    for (int d2 = 1; d2 < 64; d2 <<= 1) { sum += __shfl_xor(sum, d2); sq += __shfl_xor(sq, d2); }
    float mu = sum * (1.0f / D);
    float var = sq * (1.0f / D) - mu * mu;
    float rstd = rsqrtf(var + 1e-5f);
    const float* w = wp + (size_t)(s * L + l) * D;
    const float* b = bp + (size_t)(s * L + l) * D;
    u16x4 p0, p1;
#pragma unroll
    for (int jj = 0; jj < 4; jj++) {
        float a = (jj == 0 ? v0.x : jj == 1 ? v0.y : jj == 2 ? v0.z : v0.w);
        p0[jj] = f2bf((a - mu) * rstd * w[c0 + jj] + b[c0 + jj]);
        float c = (jj == 0 ? v1.x : jj == 1 ? v1.y : jj == 2 ? v1.z : v1.w);
        p1[jj] = f2bf((c - mu) * rstd * w[c0 + 256 + jj] + b[c0 + 256 + jj]);
    }
    *(u16x4*)(out + (size_t)row * D + c0) = p0;
    *(u16x4*)(out + (size_t)row * D + c0 + 256) = p1;
}

// ---------------- Final LayerNorm (+ bf16 partial fold) -> fp32 out --------
__global__ __launch_bounds__(256) void lnf_kernel(const u16* __restrict__ h,
                                                  const u16* __restrict__ part,
                                                  const float* __restrict__ w,
                                                  const float* __restrict__ b,
                                                  float* __restrict__ out) {
    int row = blockIdx.x * 4 + (threadIdx.x >> 6);
    int lane = threadIdx.x & 63;
    int s = row >> 11;
    int c0 = lane * 4;
    const u16* xr = h + (size_t)row * D;
    u16x4 h0 = *(const u16x4*)(xr + c0);
    u16x4 h1 = *(const u16x4*)(xr + c0 + 256);
    float4 v0, v1;
    v0.x = bf2f(h0[0]); v0.y = bf2f(h0[1]); v0.z = bf2f(h0[2]); v0.w = bf2f(h0[3]);
    v1.x = bf2f(h1[0]); v1.y = bf2f(h1[1]); v1.z = bf2f(h1[2]); v1.w = bf2f(h1[3]);
    const u16* p0r = part + (size_t)s * 2 * T * D + (size_t)(row & (T - 1)) * D;
    const u16* p1r = p0r + (size_t)T * D;
    u16x4 a0 = *(const u16x4*)(p0r + c0), a1 = *(const u16x4*)(p0r + c0 + 256);
    u16x4 e0 = *(const u16x4*)(p1r + c0), e1 = *(const u16x4*)(p1r + c0 + 256);
    v0.x += bf2f(a0[0]) + bf2f(e0[0]); v0.y += bf2f(a0[1]) + bf2f(e0[1]);
    v0.z += bf2f(a0[2]) + bf2f(e0[2]); v0.w += bf2f(a0[3]) + bf2f(e0[3]);
    v1.x += bf2f(a1[0]) + bf2f(e1[0]); v1.y += bf2f(a1[1]) + bf2f(e1[1]);
    v1.z += bf2f(a1[2]) + bf2f(e1[2]); v1.w += bf2f(a1[3]) + bf2f(e1[3]);
    float sum = v0.x + v0.y + v0.z + v0.w + v1.x + v1.y + v1.z + v1.w;
    float sq = v0.x*v0.x + v0.y*v0.y + v0.z*v0.z + v0.w*v0.w
             + v1.x*v1.x + v1.y*v1.y + v1.z*v1.z + v1.w*v1.w;
#pragma unroll
    for (int d2 = 1; d2 < 64; d2 <<= 1) { sum += __shfl_xor(sum, d2); sq += __shfl_xor(sq, d2); }
    float mu = sum * (1.0f / D);
    float var = sq * (1.0f / D) - mu * mu;
    float rstd = rsqrtf(var + 1e-5f);
    float4 r0, r1;
    r0.x = (v0.x - mu) * rstd * w[c0+0] + b[c0+0];
    r0.y = (v0.y - mu) * rstd * w[c0+1] + b[c0+1];
    r0.z = (v0.z - mu) * rstd * w[c0+2] + b[c0+2];
    r0.w = (v0.w - mu) * rstd * w[c0+3] + b[c0+3];
    r1.x = (v1.x - mu) * rstd * w[c0+256+0] + b[c0+256+0];
    r1.y = (v1.y - mu) * rstd * w[c0+256+1] + b[c0+256+1];
    r1.z = (v1.z - mu) * rstd * w[c0+256+2] + b[c0+256+2];
    r1.w = (v1.w - mu) * rstd * w[c0+256+3] + b[c0+256+3];
    *(float4*)(out + (size_t)row * D + c0) = r0;
    *(float4*)(out + (size_t)row * D + c0 + 256) = r1;
}

// ---------------- 64x64-tile bf16 GEMM, BK=64, counted-vmcnt pipeline ------
// T4 applied correctly this time: round-4's dbuf failed because __syncthreads
// emits s_waitcnt vmcnt(0) — it drained the prefetch. Here: raw s_barrier +
// inline-asm s_waitcnt vmcnt(4) (4 loads/thread/K-step; steady state 8
// outstanding, waiting to 4 = "current buffer landed, next stays in flight").
// Barrier-2 after compute protects buffer reuse (all ds_reads consumed by
// the last MFMA before a wave reaches it; no lgkm drain needed).
struct GemmPtrs {
    const u16* A[6];
    const u16* Bt[6];
    const float* bias[6];
    void* C[6];
};

#define EPI_QKV  0   // bf16 store; pidx%3==2 -> store transposed into [D][T]
#define EPI_GELU 1   // bf16 store with exact gelu
#define EPI_PART 2   // bf16 store to partial buffer C + kc*M*N

template <int EPI>
__global__ __launch_bounds__(256) void gemm_kernel(GemmPtrs p, int M, int N, int K, int KS) {
    __shared__ __align__(16) u16 lA[2][4096];
    __shared__ __align__(16) u16 lB[2][4096];
    int nchunk = K / KS;
    int pidx = blockIdx.z / nchunk;
    int kc = blockIdx.z % nchunk;
    int koff = kc * KS;
    const u16* A = p.A[pidx];
    const u16* Bt = p.Bt[pidx];
    int m0 = blockIdx.y * 64, n0 = blockIdx.x * 64;
    int tid = threadIdx.x;
    int lane = tid & 63, wave = tid >> 6;
    int wx = wave & 1, wy = wave >> 1;
    int l16 = lane & 15, q4 = lane >> 4;
    const u16* ag = A + (size_t)(m0 + (tid >> 2)) * K + koff + (tid & 3) * 8;
    const u16* bg = Bt + (size_t)(n0 + (tid >> 2)) * K + koff + (tid & 3) * 8;
    floatx4 acc[2][2] = {};
    // prologue: stage K-step 0 into buffer 0 (4 loads/thread)
#pragma unroll
    for (int kh = 0; kh < 2; kh++) {
        load_lds16(ag + kh * 32, &lA[0][kh * 2048 + tid * 8]);
        load_lds16(bg + kh * 32, &lB[0][kh * 2048 + tid * 8]);
    }
    int cur = 0;
    for (int k0 = 0; k0 < KS; k0 += 64) {
        int nxt = cur ^ 1;
        if (k0 + 64 < KS) {
            // issue next K-step's 4 loads, then wait only for the CURRENT
            // buffer's 4 (oldest) — next-buffer loads stay in flight.
#pragma unroll
            for (int kh = 0; kh < 2; kh++) {
                load_lds16(ag + k0 + 64 + kh * 32, &lA[nxt][kh * 2048 + tid * 8]);
                load_lds16(bg + k0 + 64 + kh * 32, &lB[nxt][kh * 2048 + tid * 8]);
            }
            asm volatile("s_waitcnt vmcnt(4)" ::: "memory");
        } else {
            asm volatile("s_waitcnt vmcnt(0)" ::: "memory");
        }
        __builtin_amdgcn_s_barrier();          // all waves: cur data in LDS
        __builtin_amdgcn_sched_barrier(0);     // pin ds_reads below the wait
#pragma unroll
        for (int kh = 0; kh < 2; kh++) {
            shortx8 af[2], bf[2];
#pragma unroll
            for (int t = 0; t < 2; t++) {
                af[t] = *(const shortx8*)(&lA[cur][kh * 2048 + (wy * 32 + t * 16 + l16) * 32 + q4 * 8]);
                bf[t] = *(const shortx8*)(&lB[cur][kh * 2048 + (wx * 32 + t * 16 + l16) * 32 + q4 * 8]);
            }
#pragma unroll
            for (int i = 0; i < 2; i++)
#pragma unroll
                for (int j = 0; j < 2; j++)
                    acc[i][j] = __builtin_amdgcn_mfma_f32_16x16x32_bf16(af[i], bf[j], acc[i][j], 0, 0, 0);
        }
        __builtin_amdgcn_sched_barrier(0);     // keep reads above barrier-2
        __builtin_amdgcn_s_barrier();          // protect buf[cur] reuse
        cur = nxt;
    }
    const float* bias = p.bias[pidx];
    if (EPI == EPI_QKV && (pidx % 3 == 2)) {
        // V^T epilogue: stage 64(d) x 64(t) bf16 tile in LDS (stride 72 pad),
        // then store coalesced rows of V^T[D][T]. Last K-loop barrier already
        // separates compute reads from this scratch reuse.
        u16* scr = &lA[0][0];
#pragma unroll
        for (int i = 0; i < 2; i++) {
            int tl = wy * 32 + i * 16 + q4 * 4;  // local t (row0-m0)
#pragma unroll
            for (int j = 0; j < 2; j++) {
                int dl = wx * 32 + j * 16 + l16;  // local d (col-n0)
                float bz = (kc == 0) ? bias[n0 + dl] : 0.0f;
                u16x4 pk;
#pragma unroll
                for (int r = 0; r < 4; r++) pk[r] = f2bf(acc[i][j][r] + bz);
                *(u16x4*)(scr + dl * 72 + tl) = pk;
            }
        }
        __syncthreads();
        int dl = tid >> 2, tc = (tid & 3) * 16;
        u16* dst = (u16*)p.C[pidx] + (size_t)(n0 + dl) * M + m0 + tc;
        shortx8 w0 = *(const shortx8*)(scr + dl * 72 + tc);
        shortx8 w1 = *(const shortx8*)(scr + dl * 72 + tc + 8);
        *(shortx8*)dst = w0;
        *(shortx8*)(dst + 8) = w1;
        return;
    }
#pragma unroll
    for (int i = 0; i < 2; i++) {
        int row0 = m0 + wy * 32 + i * 16 + q4 * 4;
#pragma unroll
        for (int j = 0; j < 2; j++) {
            int col = n0 + wx * 32 + j * 16 + l16;
            float bz = (kc == 0) ? bias[col] : 0.0f;
            floatx4 a = acc[i][j];
            if (EPI == EPI_QKV) {
#pragma unroll
                for (int r = 0; r < 4; r++)
                    ((u16*)p.C[pidx])[(size_t)(row0 + r) * N + col] = f2bf(a[r] + bz);
            } else if (EPI == EPI_GELU) {
#pragma unroll
                for (int r = 0; r < 4; r++) {
                    float v = a[r] + bz;
                    float g = 0.5f * v * (1.0f + erff(v * 0.70710678118f));
                    ((u16*)p.C[pidx])[(size_t)(row0 + r) * N + col] = f2bf(g);
                }
            } else {
#pragma unroll
                for (int r = 0; r < 4; r++)
                    ((u16*)p.C[pidx])[(size_t)kc * M * N + (size_t)(row0 + r) * N + col] = f2bf(a[r] + bz);
            }
        }
    }
}

// ---------------- banded flash attention, QBLK=32 --------------------------
// Block = 32 q-rows x 1 head x 1 stack; 4 waves each own interleaved 32-key
// strips (stride 128). Per strip-iter: 8 QK MFMA + 8 PV MFMA on 32x32 P tile
// (2x the MFMA per loaded K/V byte of the QBLK=16 version; halves K/V L2
// re-reads). Two-stage cross-wave reduction keeps co at 2x32x64 f32 (16KB).
__global__ __launch_bounds__(256) void attn_kernel(const u16* __restrict__ qg,
                                                   const u16* __restrict__ kg,
                                                   const u16* __restrict__ vtg,
                                                   u16* __restrict__ ao,
                                                   int bw0, int bw1) {
    __shared__ __align__(16) u16 pbuf[4][32 * 32];
    __shared__ float cl[2][32];
    __shared__ float co[2][32][64];
    int s = blockIdx.z, hh = blockIdx.y, q0 = blockIdx.x * 32;
    int bw = (s == 0) ? bw0 : bw1;
    int tid = threadIdx.x, wave = tid >> 6, lane = tid & 63;
    int l16 = lane & 15, q4 = lane >> 4;
    const u16* Q = qg + (size_t)s * T * D;
    const u16* Kp = kg + (size_t)s * T * D;
    const u16* V = vtg + (size_t)s * D * T;
    int hd = hh * DH;
    shortx8 qf[2][2];
#pragma unroll
    for (int g = 0; g < 2; g++)
#pragma unroll
        for (int hf = 0; hf < 2; hf++)
            qf[g][hf] = *(const shortx8*)(Q + (size_t)(q0 + g * 16 + l16) * D + hd + hf * 32 + q4 * 8);
    floatx4 o[2][4] = {};
    float lsum[2][4] = {};
    int klo = q0 - bw; if (klo < 0) klo = 0; klo &= ~31;
    int khi = q0 + 31;
    u16* pw = pbuf[wave];
    for (int kt = klo + wave * 32; kt <= khi; kt += 128) {
        shortx8 vf[4];
#pragma unroll
        for (int n = 0; n < 4; n++)
            vf[n] = *(const shortx8*)(V + (size_t)(hd + n * 16 + l16) * T + kt + q4 * 8);
        shortx8 kf[2][2];
#pragma unroll
        for (int t = 0; t < 2; t++)
#pragma unroll
            for (int hf = 0; hf < 2; hf++)
                kf[t][hf] = *(const shortx8*)(Kp + (size_t)(kt + t * 16 + l16) * D + hd + hf * 32 + q4 * 8);
        floatx4 sc[2][2] = {};
#pragma unroll
        for (int g = 0; g < 2; g++)
#pragma unroll
            for (int t = 0; t < 2; t++) {
                sc[g][t] = __builtin_amdgcn_mfma_f32_16x16x32_bf16(qf[g][0], kf[t][0], sc[g][t], 0, 0, 0);
                sc[g][t] = __builtin_amdgcn_mfma_f32_16x16x32_bf16(qf[g][1], kf[t][1], sc[g][t], 0, 0, 0);
            }
#pragma unroll
        for (int g = 0; g < 2; g++)
#pragma unroll
            for (int r = 0; r < 4; r++) {
                int row = q0 + g * 16 + q4 * 4 + r;
#pragma unroll
                for (int t = 0; t < 2; t++) {
                    int c = kt + t * 16 + l16;
                    float pv = (c <= row && c >= row - bw) ? __expf(sc[g][t][r] * 0.125f) : 0.0f;
                    lsum[g][r] += pv;
                    pw[(g * 16 + q4 * 4 + r) * 32 + t * 16 + l16] = f2bf(pv);
                }
            }
        shortx8 pf[2];
#pragma unroll
        for (int g = 0; g < 2; g++)
            pf[g] = *(const shortx8*)(pw + (g * 16 + l16) * 32 + q4 * 8);
#pragma unroll
        for (int g = 0; g < 2; g++)
#pragma unroll
            for (int n = 0; n < 4; n++)
                o[g][n] = __builtin_amdgcn_mfma_f32_16x16x32_bf16(pf[g], vf[n], o[g][n], 0, 0, 0);
    }
#pragma unroll
    for (int g = 0; g < 2; g++)
#pragma unroll
        for (int r = 0; r < 4; r++) {
#pragma unroll
            for (int d2 = 1; d2 < 16; d2 <<= 1) lsum[g][r] += __shfl_xor(lsum[g][r], d2);
        }
    if (wave >= 2) {
        if (l16 == 0) {
#pragma unroll
            for (int g = 0; g < 2; g++)
#pragma unroll
                for (int r = 0; r < 4; r++) cl[wave - 2][g * 16 + q4 * 4 + r] = lsum[g][r];
        }
#pragma unroll
        for (int g = 0; g < 2; g++)
#pragma unroll
            for (int n = 0; n < 4; n++)
#pragma unroll
                for (int r = 0; r < 4; r++)
                    co[wave - 2][g * 16 + q4 * 4 + r][n * 16 + l16] = o[g][n][r];
    }
    __syncthreads();
    if (wave < 2) {
        if (l16 == 0) {
#pragma unroll
            for (int g = 0; g < 2; g++)
#pragma unroll
                for (int r = 0; r < 4; r++) cl[wave][g * 16 + q4 * 4 + r] += lsum[g][r];
        }
#pragma unroll
        for (int g = 0; g < 2; g++)
#pragma unroll
            for (int n = 0; n < 4; n++)
#pragma unroll
                for (int r = 0; r < 4; r++)
                    co[wave][g * 16 + q4 * 4 + r][n * 16 + l16] += o[g][n][r];
    }
    __syncthreads();
#pragma unroll
    for (int i = 0; i < 8; i++) {
        int idx = tid + i * 256;
        int row = idx >> 6, col = idx & 63;
        float Ls = cl[0][row] + cl[1][row];
        float O = co[0][row][col] + co[1][row][col];
        ao[(size_t)s * T * D + (size_t)(q0 + row) * D + hd + col] = f2bf(O / Ls);
    }
}

// ---------------------------------------------------------------------------
extern "C" void kernel_launch(void* const* d_in, const int* in_sizes, int n_in,
                              void* d_out, int out_size, void* d_ws, size_t ws_size,
                              hipStream_t stream) {
    (void)in_sizes; (void)n_in; (void)out_size; (void)ws_size;
    const float* x     = (const float*)d_in[0];
    const float* pos   = (const float*)d_in[1];
    const float* ln1_w = (const float*)d_in[2];
    const float* ln1_b = (const float*)d_in[3];
    const float* ln2_w = (const float*)d_in[4];
    const float* ln2_b = (const float*)d_in[5];
    const float* Wq    = (const float*)d_in[6];
    const float* bq    = (const float*)d_in[7];
    const float* Wk    = (const float*)d_in[8];
    const float* bk    = (const float*)d_in[9];
    const float* Wv    = (const float*)d_in[10];
    const float* bv    = (const float*)d_in[11];
    const float* Wo    = (const float*)d_in[12];
    const float* bo    = (const float*)d_in[13];
    const float* W1    = (const float*)d_in[14];
    const float* b1    = (const float*)d_in[15];
    const float* W2    = (const float*)d_in[16];
    const float* b2    = (const float*)d_in[17];
    const float* lnf_w = (const float*)d_in[18];
    const float* lnf_b = (const float*)d_in[19];

    char* ws = (char*)d_ws;
    size_t off = 0;
    auto alloc = [&](size_t bytes) { void* p = ws + off; off += (bytes + 255) & ~(size_t)255; return p; };
    u16* WqT = (u16*)alloc((size_t)4 * 512 * 512 * 2);
    u16* WkT = (u16*)alloc((size_t)4 * 512 * 512 * 2);
    u16* WvT = (u16*)alloc((size_t)4 * 512 * 512 * 2);
    u16* WoT = (u16*)alloc((size_t)4 * 512 * 512 * 2);
    u16* W1T = (u16*)alloc((size_t)4 * 512 * 1024 * 2);
    u16* W2T = (u16*)alloc((size_t)4 * 1024 * 512 * 2);
    u16* h   = (u16*)alloc((size_t)2 * T * D * 2);
    u16* xln = (u16*)alloc((size_t)2 * T * D * 2);
    u16* qb  = (u16*)alloc((size_t)2 * T * D * 2);
    u16* kb  = (u16*)alloc((size_t)2 * T * D * 2);
    u16* vt  = (u16*)alloc((size_t)2 * T * D * 2);
    u16* ao  = (u16*)alloc((size_t)2 * T * D * 2);
    u16* ff  = (u16*)alloc((size_t)2 * T * 1024 * 2);
    u16* pp = (u16*)alloc((size_t)2 * 2 * T * D * 2);  // proj partials bf16 [s][2][T][D]
    u16* pf = (u16*)alloc((size_t)2 * 2 * T * D * 2);  // ff2 partials bf16

    TransJobs tj;
    tj.src[0] = Wq; tj.dst[0] = WqT;
    tj.src[1] = Wk; tj.dst[1] = WkT;
    tj.src[2] = Wv; tj.dst[2] = WvT;
    tj.src[3] = Wo; tj.dst[3] = WoT;
    tj.src[4] = W1; tj.dst[4] = W1T;
    tj.src[5] = W2; tj.dst[5] = W2T;
    tj.x = x; tj.pos = pos; tj.h = h;
    pre_kernel<<<dim3(32, 32, 25), 256, 0, stream>>>(tj);

    for (int l = 0; l < L; l++) {
        ln_res_kernel<<<(2 * T) / 4, 256, 0, stream>>>(h, l == 0 ? nullptr : pf,
                                                       ln1_w, ln1_b, xln, l);

        GemmPtrs g{};
        for (int s = 0; s < 2; s++) {
            int wo = s * L + l;
            const u16* a = xln + (size_t)s * T * D;
            g.A[s * 3 + 0] = a; g.Bt[s * 3 + 0] = WqT + (size_t)wo * 512 * 512;
            g.bias[s * 3 + 0] = bq + (size_t)wo * 512; g.C[s * 3 + 0] = qb + (size_t)s * T * D;
            g.A[s * 3 + 1] = a; g.Bt[s * 3 + 1] = WkT + (size_t)wo * 512 * 512;
            g.bias[s * 3 + 1] = bk + (size_t)wo * 512; g.C[s * 3 + 1] = kb + (size_t)s * T * D;
            g.A[s * 3 + 2] = a; g.Bt[s * 3 + 2] = WvT + (size_t)wo * 512 * 512;
            g.bias[s * 3 + 2] = bv + (size_t)wo * 512; g.C[s * 3 + 2] = vt + (size_t)s * T * D;
        }
        gemm_kernel<EPI_QKV><<<dim3(8, 32, 6), 256, 0, stream>>>(g, T, 512, 512, 512);

        attn_kernel<<<dim3(64, 8, 2), 256, 0, stream>>>(qb, kb, vt, ao, 999, 9);

        GemmPtrs gp{};
        for (int s = 0; s < 2; s++) {
            int wo = s * L + l;
            gp.A[s] = ao + (size_t)s * T * D;
            gp.Bt[s] = WoT + (size_t)wo * 512 * 512;
            gp.bias[s] = bo + (size_t)wo * 512;
            gp.C[s] = pp + (size_t)s * 2 * T * D;
        }
        gemm_kernel<EPI_PART><<<dim3(8, 32, 4), 256, 0, stream>>>(gp, T, 512, 512, 256);

        ln_res_kernel<<<(2 * T) / 4, 256, 0, stream>>>(h, pp, ln2_w, ln2_b, xln, l);

        GemmPtrs g1{};
        for (int s = 0; s < 2; s++) {
            int wo = s * L + l;
            g1.A[s] = xln + (size_t)s * T * D;
            g1.Bt[s] = W1T + (size_t)wo * 512 * 1024;
            g1.bias[s] = b1 + (size_t)wo * 1024;
            g1.C[s] = ff + (size_t)s * T * 1024;
        }
        gemm_kernel<EPI_GELU><<<dim3(16, 32, 2), 256, 0, stream>>>(g1, T, 1024, 512, 512);

        GemmPtrs g2{};
        for (int s = 0; s < 2; s++) {
            int wo = s * L + l;
            g2.A[s] = ff + (size_t)s * T * 1024;
            g2.Bt[s] = W2T + (size_t)wo * 1024 * 512;
            g2.bias[s] = b2 + (size_t)wo * 512;
            g2.C[s] = pf + (size_t)s * 2 * T * D;
        }
        gemm_kernel<EPI_PART><<<dim3(8, 32, 4), 256, 0, stream>>>(g2, T, 512, 1024, 512);
    }

    lnf_kernel<<<(2 * T) / 4, 256, 0, stream>>>(h, pf, lnf_w, lnf_b, (float*)d_out);
}

// Round 8
// 293.712 us; speedup vs baseline: 1.0317x; 1.0317x over previous
//
#include <hip/hip_runtime.h>
#include <stdint.h>

#define T 2048
#define D 512
#define NH 8
#define DH 64
#define L 2

typedef float floatx4 __attribute__((ext_vector_type(4)));
typedef short shortx8 __attribute__((ext_vector_type(8)));
typedef unsigned short u16;
typedef unsigned short u16x4 __attribute__((ext_vector_type(4)));

__device__ __forceinline__ u16 f2bf(float f) {
    union { float f; uint32_t u; } c; c.f = f;
    uint32_t u = c.u;
    u += 0x7fffu + ((u >> 16) & 1u);
    return (u16)(u >> 16);
}

__device__ __forceinline__ float bf2f(u16 v) {
    union { uint32_t u; float f; } c; c.u = ((uint32_t)v) << 16;
    return c.f;
}

__device__ __forceinline__ void load_lds16(const void* g, void* l) {
    __builtin_amdgcn_global_load_lds((const __attribute__((address_space(1))) void*)g,
                                     (__attribute__((address_space(3))) void*)l,
                                     16, 0, 0);
}

// ---------------- pre: weight transposes (z<24) + add_pos (z==24) ----------
struct TransJobs {
    const float* src[6];
    u16* dst[6];
    const float* x;
    const float* pos;
    u16* h;
};

__global__ __launch_bounds__(256) void pre_kernel(TransJobs j) {
    __shared__ float tile[32][33];
    int tid = threadIdx.x;
    if (blockIdx.z == 24) {
        int idx = (blockIdx.y * 32 + blockIdx.x) * 256 + tid;  // float4 index
        float4 xv = ((const float4*)j.x)[idx];
        float4 pv = ((const float4*)j.pos)[idx];
        u16x4 hh;
        hh[0] = f2bf(xv.x + pv.x); hh[1] = f2bf(xv.y + pv.y);
        hh[2] = f2bf(xv.z + pv.z); hh[3] = f2bf(xv.w + pv.w);
        ((u16x4*)j.h)[idx] = hh;
        ((u16x4*)j.h)[idx + (T * D / 4)] = hh;
        return;
    }
    int m = blockIdx.z >> 2, slice = blockIdx.z & 3;
    int R = (m == 5) ? 1024 : 512;
    int C = (m == 4) ? 1024 : 512;
    if (blockIdx.x * 32 >= C || blockIdx.y * 32 >= R) return;
    const float* in = j.src[m] + (size_t)slice * R * C;
    u16* out = j.dst[m] + (size_t)slice * R * C;
    int tx = tid & 31, ty = tid >> 5;
    int x = blockIdx.x * 32 + tx;
    int y0 = blockIdx.y * 32;
#pragma unroll
    for (int i = 0; i < 4; i++)
        tile[ty + i * 8][tx] = in[(size_t)(y0 + ty + i * 8) * C + x];
    __syncthreads();
    int ox = y0 + tx;
#pragma unroll
    for (int i = 0; i < 4; i++)
        out[(size_t)(blockIdx.x * 32 + ty + i * 8) * R + ox] = f2bf(tile[tx][ty + i * 8]);
}

// ---------------- LayerNorm over bf16 h + optional bf16-partial fold -------
__global__ __launch_bounds__(256) void ln_res_kernel(u16* __restrict__ h,
                                                     const u16* __restrict__ part,
                                                     const float* __restrict__ wp,
                                                     const float* __restrict__ bp,
                                                     u16* __restrict__ out, int l) {
    int row = blockIdx.x * 4 + (threadIdx.x >> 6);
    int lane = threadIdx.x & 63;
    int s = row >> 11;
    int c0 = lane * 4;
    u16* xr = h + (size_t)row * D;
    u16x4 h0 = *(const u16x4*)(xr + c0);
    u16x4 h1 = *(const u16x4*)(xr + c0 + 256);
    float4 v0, v1;
    v0.x = bf2f(h0[0]); v0.y = bf2f(h0[1]); v0.z = bf2f(h0[2]); v0.w = bf2f(h0[3]);
    v1.x = bf2f(h1[0]); v1.y = bf2f(h1[1]); v1.z = bf2f(h1[2]); v1.w = bf2f(h1[3]);
    if (part) {
        const u16* p0r = part + (size_t)s * 2 * T * D + (size_t)(row & (T - 1)) * D;
        const u16* p1r = p0r + (size_t)T * D;
        u16x4 a0 = *(const u16x4*)(p0r + c0), a1 = *(const u16x4*)(p0r + c0 + 256);
        u16x4 e0 = *(const u16x4*)(p1r + c0), e1 = *(const u16x4*)(p1r + c0 + 256);
        v0.x += bf2f(a0[0]) + bf2f(e0[0]); v0.y += bf2f(a0[1]) + bf2f(e0[1]);
        v0.z += bf2f(a0[2]) + bf2f(e0[2]); v0.w += bf2f(a0[3]) + bf2f(e0[3]);
        v1.x += bf2f(a1[0]) + bf2f(e1[0]); v1.y += bf2f(a1[1]) + bf2f(e1[1]);
        v1.z += bf2f(a1[2]) + bf2f(e1[2]); v1.w += bf2f(a1[3]) + bf2f(e1[3]);
        u16x4 s0, s1;
        s0[0] = f2bf(v0.x); s0[1] = f2bf(v0.y); s0[2] = f2bf(v0.z); s0[3] = f2bf(v0.w);
        s1[0] = f2bf(v1.x); s1[1] = f2bf(v1.y); s1[2] = f2bf(v1.z); s1[3] = f2bf(v1.w);
        *(u16x4*)(xr + c0) = s0;
        *(u16x4*)(xr + c0 + 256) = s1;
    }
    float sum = v0.x + v0.y + v0.z + v0.w + v1.x + v1.y + v1.z + v1.w;
    float sq = v0.x*v0.x + v0.y*v0.y + v0.z*v0.z + v0.w*v0.w
             + v1.x*v1.x + v1.y*v1.y + v1.z*v1.z + v1.w*v1.w;
#pragma unroll
    for (int d2 = 1; d2 < 64; d2 <<= 1) { sum += __shfl_xor(sum, d2); sq += __shfl_xor(sq, d2); }
    float mu = sum * (1.0f / D);
    float var = sq * (1.0f / D) - mu * mu;
    float rstd = rsqrtf(var + 1e-5f);
    const float* w = wp + (size_t)(s * L + l) * D;
    const float* b = bp + (size_t)(s * L + l) * D;
    u16x4 p0, p1;
#pragma unroll
    for (int jj = 0; jj < 4; jj++) {
        float a = (jj == 0 ? v0.x : jj == 1 ? v0.y : jj == 2 ? v0.z : v0.w);
        p0[jj] = f2bf((a - mu) * rstd * w[c0 + jj] + b[c0 + jj]);
        float c = (jj == 0 ? v1.x : jj == 1 ? v1.y : jj == 2 ? v1.z : v1.w);
        p1[jj] = f2bf((c - mu) * rstd * w[c0 + 256 + jj] + b[c0 + 256 + jj]);
    }
    *(u16x4*)(out + (size_t)row * D + c0) = p0;
    *(u16x4*)(out + (size_t)row * D + c0 + 256) = p1;
}

// ---------------- Final LayerNorm (+ bf16 partial fold) -> fp32 out --------
__global__ __launch_bounds__(256) void lnf_kernel(const u16* __restrict__ h,
                                                  const u16* __restrict__ part,
                                                  const float* __restrict__ w,
                                                  const float* __restrict__ b,
                                                  float* __restrict__ out) {
    int row = blockIdx.x * 4 + (threadIdx.x >> 6);
    int lane = threadIdx.x & 63;
    int s = row >> 11;
    int c0 = lane * 4;
    const u16* xr = h + (size_t)row * D;
    u16x4 h0 = *(const u16x4*)(xr + c0);
    u16x4 h1 = *(const u16x4*)(xr + c0 + 256);
    float4 v0, v1;
    v0.x = bf2f(h0[0]); v0.y = bf2f(h0[1]); v0.z = bf2f(h0[2]); v0.w = bf2f(h0[3]);
    v1.x = bf2f(h1[0]); v1.y = bf2f(h1[1]); v1.z = bf2f(h1[2]); v1.w = bf2f(h1[3]);
    const u16* p0r = part + (size_t)s * 2 * T * D + (size_t)(row & (T - 1)) * D;
    const u16* p1r = p0r + (size_t)T * D;
    u16x4 a0 = *(const u16x4*)(p0r + c0), a1 = *(const u16x4*)(p0r + c0 + 256);
    u16x4 e0 = *(const u16x4*)(p1r + c0), e1 = *(const u16x4*)(p1r + c0 + 256);
    v0.x += bf2f(a0[0]) + bf2f(e0[0]); v0.y += bf2f(a0[1]) + bf2f(e0[1]);
    v0.z += bf2f(a0[2]) + bf2f(e0[2]); v0.w += bf2f(a0[3]) + bf2f(e0[3]);
    v1.x += bf2f(a1[0]) + bf2f(e1[0]); v1.y += bf2f(a1[1]) + bf2f(e1[1]);
    v1.z += bf2f(a1[2]) + bf2f(e1[2]); v1.w += bf2f(a1[3]) + bf2f(e1[3]);
    float sum = v0.x + v0.y + v0.z + v0.w + v1.x + v1.y + v1.z + v1.w;
    float sq = v0.x*v0.x + v0.y*v0.y + v0.z*v0.z + v0.w*v0.w
             + v1.x*v1.x + v1.y*v1.y + v1.z*v1.z + v1.w*v1.w;
#pragma unroll
    for (int d2 = 1; d2 < 64; d2 <<= 1) { sum += __shfl_xor(sum, d2); sq += __shfl_xor(sq, d2); }
    float mu = sum * (1.0f / D);
    float var = sq * (1.0f / D) - mu * mu;
    float rstd = rsqrtf(var + 1e-5f);
    float4 r0, r1;
    r0.x = (v0.x - mu) * rstd * w[c0+0] + b[c0+0];
    r0.y = (v0.y - mu) * rstd * w[c0+1] + b[c0+1];
    r0.z = (v0.z - mu) * rstd * w[c0+2] + b[c0+2];
    r0.w = (v0.w - mu) * rstd * w[c0+3] + b[c0+3];
    r1.x = (v1.x - mu) * rstd * w[c0+256+0] + b[c0+256+0];
    r1.y = (v1.y - mu) * rstd * w[c0+256+1] + b[c0+256+1];
    r1.z = (v1.z - mu) * rstd * w[c0+256+2] + b[c0+256+2];
    r1.w = (v1.w - mu) * rstd * w[c0+256+3] + b[c0+256+3];
    *(float4*)(out + (size_t)row * D + c0) = r0;
    *(float4*)(out + (size_t)row * D + c0 + 256) = r1;
}

// ---------------- 64x64-tile bf16 GEMM, BK=64 (round-3 base) ---------------
// New vs round-3: ALL epilogues (not just V^T) stage the 64x64 output tile
// in LDS (stride-72 pad) and store coalesced 128B rows. Previously Q/K/
// partial/gelu stores were 2B scatters at row-stride N (4 lines touched per
// store instr, ~25% line efficiency on ~56MB of stores per forward).
struct GemmPtrs {
    const u16* A[6];
    const u16* Bt[6];
    const float* bias[6];
    void* C[6];
};

#define EPI_QKV  0   // bf16 store; pidx%3==2 -> store transposed into [D][T]
#define EPI_GELU 1   // bf16 store with exact gelu
#define EPI_PART 2   // bf16 store to partial buffer C + kc*M*N

template <int EPI>
__global__ __launch_bounds__(256) void gemm_kernel(GemmPtrs p, int M, int N, int K, int KS) {
    __shared__ __align__(16) u16 smem[8192];  // lA[2][2048] | lB[2][2048]
    u16* lA = smem;
    u16* lB = smem + 4096;
    int nchunk = K / KS;
    int pidx = blockIdx.z / nchunk;
    int kc = blockIdx.z % nchunk;
    int koff = kc * KS;
    const u16* A = p.A[pidx];
    const u16* Bt = p.Bt[pidx];
    int m0 = blockIdx.y * 64, n0 = blockIdx.x * 64;
    int tid = threadIdx.x;
    int lane = tid & 63, wave = tid >> 6;
    int wx = wave & 1, wy = wave >> 1;
    int l16 = lane & 15, q4 = lane >> 4;
    const u16* ag = A + (size_t)(m0 + (tid >> 2)) * K + koff + (tid & 3) * 8;
    const u16* bg = Bt + (size_t)(n0 + (tid >> 2)) * K + koff + (tid & 3) * 8;
    floatx4 acc[2][2] = {};
    for (int k0 = 0; k0 < KS; k0 += 64) {
        __syncthreads();
#pragma unroll
        for (int kh = 0; kh < 2; kh++) {
            load_lds16(ag + k0 + kh * 32, lA + kh * 2048 + tid * 8);
            load_lds16(bg + k0 + kh * 32, lB + kh * 2048 + tid * 8);
        }
        __syncthreads();
#pragma unroll
        for (int kh = 0; kh < 2; kh++) {
            shortx8 af[2], bf[2];
#pragma unroll
            for (int t = 0; t < 2; t++) {
                af[t] = *(const shortx8*)(lA + kh * 2048 + (wy * 32 + t * 16 + l16) * 32 + q4 * 8);
                bf[t] = *(const shortx8*)(lB + kh * 2048 + (wx * 32 + t * 16 + l16) * 32 + q4 * 8);
            }
#pragma unroll
            for (int i = 0; i < 2; i++)
#pragma unroll
                for (int j = 0; j < 2; j++)
                    acc[i][j] = __builtin_amdgcn_mfma_f32_16x16x32_bf16(af[i], bf[j], acc[i][j], 0, 0, 0);
        }
    }
    const float* bias = p.bias[pidx];
    __syncthreads();  // LDS reuse: all compute reads done
    if (EPI == EPI_QKV && (pidx % 3 == 2)) {
        // V^T epilogue (verified round-3): stage transposed [d][t], store
        // coalesced rows of V^T[D][T].
#pragma unroll
        for (int i = 0; i < 2; i++) {
            int tl = wy * 32 + i * 16 + q4 * 4;  // local t
#pragma unroll
            for (int j = 0; j < 2; j++) {
                int dl = wx * 32 + j * 16 + l16;  // local d
                float bz = (kc == 0) ? bias[n0 + dl] : 0.0f;
                u16x4 pk;
#pragma unroll
                for (int r = 0; r < 4; r++) pk[r] = f2bf(acc[i][j][r] + bz);
                *(u16x4*)(smem + dl * 72 + tl) = pk;
            }
        }
        __syncthreads();
        int dl = tid >> 2, tc = (tid & 3) * 16;
        u16* dst = (u16*)p.C[pidx] + (size_t)(n0 + dl) * M + m0 + tc;
        shortx8 w0 = *(const shortx8*)(smem + dl * 72 + tc);
        shortx8 w1 = *(const shortx8*)(smem + dl * 72 + tc + 8);
        *(shortx8*)dst = w0;
        *(shortx8*)(dst + 8) = w1;
        return;
    }
    // Natural-orientation epilogue: stage [t][d] (stride 72), apply bias
    // (+gelu for EPI_GELU) in-register, then store 64 coalesced 128B rows.
#pragma unroll
    for (int i = 0; i < 2; i++) {
        int tl0 = wy * 32 + i * 16 + q4 * 4;
#pragma unroll
        for (int j = 0; j < 2; j++) {
            int dl = wx * 32 + j * 16 + l16;
            float bz = (kc == 0) ? bias[n0 + dl] : 0.0f;
#pragma unroll
            for (int r = 0; r < 4; r++) {
                float v = acc[i][j][r] + bz;
                if (EPI == EPI_GELU)
                    v = 0.5f * v * (1.0f + erff(v * 0.70710678118f));
                smem[(tl0 + r) * 72 + dl] = f2bf(v);
            }
        }
    }
    __syncthreads();
    {
        int tl = tid >> 2, dc = (tid & 3) * 16;
        u16* dst = (u16*)p.C[pidx]
                 + (EPI == EPI_PART ? (size_t)kc * M * N : (size_t)0)
                 + (size_t)(m0 + tl) * N + n0 + dc;
        shortx8 w0 = *(const shortx8*)(smem + tl * 72 + dc);
        shortx8 w1 = *(const shortx8*)(smem + tl * 72 + dc + 8);
        *(shortx8*)dst = w0;
        *(shortx8*)(dst + 8) = w1;
    }
}

// ---------------- banded flash attention, QBLK=32 (round-3, verified) ------
__global__ __launch_bounds__(256) void attn_kernel(const u16* __restrict__ qg,
                                                   const u16* __restrict__ kg,
                                                   const u16* __restrict__ vtg,
                                                   u16* __restrict__ ao,
                                                   int bw0, int bw1) {
    __shared__ __align__(16) u16 pbuf[4][32 * 32];
    __shared__ float cl[2][32];
    __shared__ float co[2][32][64];
    int s = blockIdx.z, hh = blockIdx.y, q0 = blockIdx.x * 32;
    int bw = (s == 0) ? bw0 : bw1;
    int tid = threadIdx.x, wave = tid >> 6, lane = tid & 63;
    int l16 = lane & 15, q4 = lane >> 4;
    const u16* Q = qg + (size_t)s * T * D;
    const u16* Kp = kg + (size_t)s * T * D;
    const u16* V = vtg + (size_t)s * D * T;
    int hd = hh * DH;
    shortx8 qf[2][2];
#pragma unroll
    for (int g = 0; g < 2; g++)
#pragma unroll
        for (int hf = 0; hf < 2; hf++)
            qf[g][hf] = *(const shortx8*)(Q + (size_t)(q0 + g * 16 + l16) * D + hd + hf * 32 + q4 * 8);
    floatx4 o[2][4] = {};
    float lsum[2][4] = {};
    int klo = q0 - bw; if (klo < 0) klo = 0; klo &= ~31;
    int khi = q0 + 31;
    u16* pw = pbuf[wave];
    for (int kt = klo + wave * 32; kt <= khi; kt += 128) {
        shortx8 vf[4];
#pragma unroll
        for (int n = 0; n < 4; n++)
            vf[n] = *(const shortx8*)(V + (size_t)(hd + n * 16 + l16) * T + kt + q4 * 8);
        shortx8 kf[2][2];
#pragma unroll
        for (int t = 0; t < 2; t++)
#pragma unroll
            for (int hf = 0; hf < 2; hf++)
                kf[t][hf] = *(const shortx8*)(Kp + (size_t)(kt + t * 16 + l16) * D + hd + hf * 32 + q4 * 8);
        floatx4 sc[2][2] = {};
#pragma unroll
        for (int g = 0; g < 2; g++)
#pragma unroll
            for (int t = 0; t < 2; t++) {
                sc[g][t] = __builtin_amdgcn_mfma_f32_16x16x32_bf16(qf[g][0], kf[t][0], sc[g][t], 0, 0, 0);
                sc[g][t] = __builtin_amdgcn_mfma_f32_16x16x32_bf16(qf[g][1], kf[t][1], sc[g][t], 0, 0, 0);
            }
#pragma unroll
        for (int g = 0; g < 2; g++)
#pragma unroll
            for (int r = 0; r < 4; r++) {
                int row = q0 + g * 16 + q4 * 4 + r;
#pragma unroll
                for (int t = 0; t < 2; t++) {
                    int c = kt + t * 16 + l16;
                    float pv = (c <= row && c >= row - bw) ? __expf(sc[g][t][r] * 0.125f) : 0.0f;
                    lsum[g][r] += pv;
                    pw[(g * 16 + q4 * 4 + r) * 32 + t * 16 + l16] = f2bf(pv);
                }
            }
        shortx8 pf[2];
#pragma unroll
        for (int g = 0; g < 2; g++)
            pf[g] = *(const shortx8*)(pw + (g * 16 + l16) * 32 + q4 * 8);
#pragma unroll
        for (int g = 0; g < 2; g++)
#pragma unroll
            for (int n = 0; n < 4; n++)
                o[g][n] = __builtin_amdgcn_mfma_f32_16x16x32_bf16(pf[g], vf[n], o[g][n], 0, 0, 0);
    }
#pragma unroll
    for (int g = 0; g < 2; g++)
#pragma unroll
        for (int r = 0; r < 4; r++) {
#pragma unroll
            for (int d2 = 1; d2 < 16; d2 <<= 1) lsum[g][r] += __shfl_xor(lsum[g][r], d2);
        }
    if (wave >= 2) {
        if (l16 == 0) {
#pragma unroll
            for (int g = 0; g < 2; g++)
#pragma unroll
                for (int r = 0; r < 4; r++) cl[wave - 2][g * 16 + q4 * 4 + r] = lsum[g][r];
        }
#pragma unroll
        for (int g = 0; g < 2; g++)
#pragma unroll
            for (int n = 0; n < 4; n++)
#pragma unroll
                for (int r = 0; r < 4; r++)
                    co[wave - 2][g * 16 + q4 * 4 + r][n * 16 + l16] = o[g][n][r];
    }
    __syncthreads();
    if (wave < 2) {
        if (l16 == 0) {
#pragma unroll
            for (int g = 0; g < 2; g++)
#pragma unroll
                for (int r = 0; r < 4; r++) cl[wave][g * 16 + q4 * 4 + r] += lsum[g][r];
        }
#pragma unroll
        for (int g = 0; g < 2; g++)
#pragma unroll
            for (int n = 0; n < 4; n++)
#pragma unroll
                for (int r = 0; r < 4; r++)
                    co[wave][g * 16 + q4 * 4 + r][n * 16 + l16] += o[g][n][r];
    }
    __syncthreads();
#pragma unroll
    for (int i = 0; i < 8; i++) {
        int idx = tid + i * 256;
        int row = idx >> 6, col = idx & 63;
        float Ls = cl[0][row] + cl[1][row];
        float O = co[0][row][col] + co[1][row][col];
        ao[(size_t)s * T * D + (size_t)(q0 + row) * D + hd + col] = f2bf(O / Ls);
    }
}

// ---------------------------------------------------------------------------
extern "C" void kernel_launch(void* const* d_in, const int* in_sizes, int n_in,
                              void* d_out, int out_size, void* d_ws, size_t ws_size,
                              hipStream_t stream) {
    (void)in_sizes; (void)n_in; (void)out_size; (void)ws_size;
    const float* x     = (const float*)d_in[0];
    const float* pos   = (const float*)d_in[1];
    const float* ln1_w = (const float*)d_in[2];
    const float* ln1_b = (const float*)d_in[3];
    const float* ln2_w = (const float*)d_in[4];
    const float* ln2_b = (const float*)d_in[5];
    const float* Wq    = (const float*)d_in[6];
    const float* bq    = (const float*)d_in[7];
    const float* Wk    = (const float*)d_in[8];
    const float* bk    = (const float*)d_in[9];
    const float* Wv    = (const float*)d_in[10];
    const float* bv    = (const float*)d_in[11];
    const float* Wo    = (const float*)d_in[12];
    const float* bo    = (const float*)d_in[13];
    const float* W1    = (const float*)d_in[14];
    const float* b1    = (const float*)d_in[15];
    const float* W2    = (const float*)d_in[16];
    const float* b2    = (const float*)d_in[17];
    const float* lnf_w = (const float*)d_in[18];
    const float* lnf_b = (const float*)d_in[19];

    char* ws = (char*)d_ws;
    size_t off = 0;
    auto alloc = [&](size_t bytes) { void* p = ws + off; off += (bytes + 255) & ~(size_t)255; return p; };
    u16* WqT = (u16*)alloc((size_t)4 * 512 * 512 * 2);
    u16* WkT = (u16*)alloc((size_t)4 * 512 * 512 * 2);
    u16* WvT = (u16*)alloc((size_t)4 * 512 * 512 * 2);
    u16* WoT = (u16*)alloc((size_t)4 * 512 * 512 * 2);
    u16* W1T = (u16*)alloc((size_t)4 * 512 * 1024 * 2);
    u16* W2T = (u16*)alloc((size_t)4 * 1024 * 512 * 2);
    u16* h   = (u16*)alloc((size_t)2 * T * D * 2);
    u16* xln = (u16*)alloc((size_t)2 * T * D * 2);
    u16* qb  = (u16*)alloc((size_t)2 * T * D * 2);
    u16* kb  = (u16*)alloc((size_t)2 * T * D * 2);
    u16* vt  = (u16*)alloc((size_t)2 * T * D * 2);
    u16* ao  = (u16*)alloc((size_t)2 * T * D * 2);
    u16* ff  = (u16*)alloc((size_t)2 * T * 1024 * 2);
    u16* pp = (u16*)alloc((size_t)2 * 2 * T * D * 2);  // proj partials bf16 [s][2][T][D]
    u16* pf = (u16*)alloc((size_t)2 * 2 * T * D * 2);  // ff2 partials bf16

    TransJobs tj;
    tj.src[0] = Wq; tj.dst[0] = WqT;
    tj.src[1] = Wk; tj.dst[1] = WkT;
    tj.src[2] = Wv; tj.dst[2] = WvT;
    tj.src[3] = Wo; tj.dst[3] = WoT;
    tj.src[4] = W1; tj.dst[4] = W1T;
    tj.src[5] = W2; tj.dst[5] = W2T;
    tj.x = x; tj.pos = pos; tj.h = h;
    pre_kernel<<<dim3(32, 32, 25), 256, 0, stream>>>(tj);

    for (int l = 0; l < L; l++) {
        ln_res_kernel<<<(2 * T) / 4, 256, 0, stream>>>(h, l == 0 ? nullptr : pf,
                                                       ln1_w, ln1_b, xln, l);

        GemmPtrs g{};
        for (int s = 0; s < 2; s++) {
            int wo = s * L + l;
            const u16* a = xln + (size_t)s * T * D;
            g.A[s * 3 + 0] = a; g.Bt[s * 3 + 0] = WqT + (size_t)wo * 512 * 512;
            g.bias[s * 3 + 0] = bq + (size_t)wo * 512; g.C[s * 3 + 0] = qb + (size_t)s * T * D;
            g.A[s * 3 + 1] = a; g.Bt[s * 3 + 1] = WkT + (size_t)wo * 512 * 512;
            g.bias[s * 3 + 1] = bk + (size_t)wo * 512; g.C[s * 3 + 1] = kb + (size_t)s * T * D;
            g.A[s * 3 + 2] = a; g.Bt[s * 3 + 2] = WvT + (size_t)wo * 512 * 512;
            g.bias[s * 3 + 2] = bv + (size_t)wo * 512; g.C[s * 3 + 2] = vt + (size_t)s * T * D;
        }
        gemm_kernel<EPI_QKV><<<dim3(8, 32, 6), 256, 0, stream>>>(g, T, 512, 512, 512);

        attn_kernel<<<dim3(64, 8, 2), 256, 0, stream>>>(qb, kb, vt, ao, 999, 9);

        GemmPtrs gp{};
        for (int s = 0; s < 2; s++) {
            int wo = s * L + l;
            gp.A[s] = ao + (size_t)s * T * D;
            gp.Bt[s] = WoT + (size_t)wo * 512 * 512;
            gp.bias[s] = bo + (size_t)wo * 512;
            gp.C[s] = pp + (size_t)s * 2 * T * D;
        }
        gemm_kernel<EPI_PART><<<dim3(8, 32, 4), 256, 0, stream>>>(gp, T, 512, 512, 256);

        ln_res_kernel<<<(2 * T) / 4, 256, 0, stream>>>(h, pp, ln2_w, ln2_b, xln, l);

        GemmPtrs g1{};
        for (int s = 0; s < 2; s++) {
            int wo = s * L + l;
            g1.A[s] = xln + (size_t)s * T * D;
            g1.Bt[s] = W1T + (size_t)wo * 512 * 1024;
            g1.bias[s] = b1 + (size_t)wo * 1024;
            g1.C[s] = ff + (size_t)s * T * 1024;
        }
        gemm_kernel<EPI_GELU><<<dim3(16, 32, 2), 256, 0, stream>>>(g1, T, 1024, 512, 512);

        GemmPtrs g2{};
        for (int s = 0; s < 2; s++) {
            int wo = s * L + l;
            g2.A[s] = ff + (size_t)s * T * 1024;
            g2.Bt[s] = W2T + (size_t)wo * 1024 * 512;
            g2.bias[s] = b2 + (size_t)wo * 512;
            g2.C[s] = pf + (size_t)s * 2 * T * D;
        }
        gemm_kernel<EPI_PART><<<dim3(8, 32, 4), 256, 0, stream>>>(g2, T, 512, 1024, 512);
    }

    lnf_kernel<<<(2 * T) / 4, 256, 0, stream>>>(h, pf, lnf_w, lnf_b, (float*)d_out);
}